// Round 6
// baseline (144.069 us; speedup 1.0000x reference)
//
#include <hip/hip_runtime.h>
#include <math.h>

#define B 8
#define C 32
#define H 384
#define W 384
#define HW (H*W)

typedef float f4 __attribute__((ext_vector_type(4)));
typedef float f2 __attribute__((ext_vector_type(2)));

// tanh via fast exp; offsets only shift sample coords, error negligible.
__device__ __forceinline__ float fast_tanh(float v) {
    float t = __expf(2.0f * v);
    return 1.0f - 2.0f / (t + 1.0f);
}

// Reflection over [-0.5, size-0.5] then clip. Drift |ix - w| <= 1.503 =>
// xr < 2*size, one fold suffices.
__device__ __forceinline__ float reflect_fast(float coord, float span) {
    float xr = fabsf(coord + 0.5f);
    float out = (xr < span) ? (xr - 0.5f) : (2.0f * span - xr - 0.5f);
    return fminf(fmaxf(out, 0.0f), span - 1.0f);
}

// ================= offset kernel (v6) =================
// 64x16 tile (1152 blocks), stage rows [h0-1,h0+17) x cols [w0-4,w0+68)
// zero-padded. Double-buffered LDS, 2-deep register prefetch, 1 barrier/ch.
#define K1R 18
#define K1S 72
#define K1_SLOTS (K1R * 18)      // 324 f4 slots

__global__ __launch_bounds__(256) void offset_kernel(
        const float* __restrict__ x,
        const float* __restrict__ ow,
        const float* __restrict__ ob,
        float2* __restrict__ ws) {
    __shared__ float xs[2][K1R * K1S];

    const int tid = threadIdx.x;
    const int b_ = blockIdx.z;
    const int h0 = blockIdx.y * 16;
    const int w0 = blockIdx.x * 64;
    const float* xb = x + (size_t)b_ * C * HW;

    // channel-invariant staging descriptors (zero-pad semantics)
    int  goff[2], loff[2];
    bool gok[2], slot[2];
    #pragma unroll
    for (int k = 0; k < 2; ++k) {
        int idx = tid + k * 256;
        slot[k] = (idx < K1_SLOTS);
        int row = idx / 18, k4 = idx - row * 18;
        int grow = h0 - 1 + row;
        int gcol = w0 - 4 + k4 * 4;
        gok[k] = slot[k] && grow >= 0 && grow < H && gcol >= 0 && (gcol + 3) < W;
        goff[k] = max(grow, 0) * W + max(gcol, 0);
        loff[k] = row * K1S + k4 * 4;
    }

#define K1_LOAD(PF, cc) do {                                            \
        const float* xc_ = xb + (size_t)(cc) * HW;                      \
        _Pragma("unroll")                                               \
        for (int k = 0; k < 2; ++k)                                     \
            PF[k] = gok[k] ? *(const f4*)(xc_ + goff[k]) : (f4)0.0f;    \
    } while (0)
#define K1_WRITE(bufi, PF) do {                                         \
        float* dst_ = xs[bufi];                                         \
        _Pragma("unroll")                                               \
        for (int k = 0; k < 2; ++k)                                     \
            if (slot[k]) *(f4*)&dst_[loff[k]] = PF[k];                  \
    } while (0)

    const int tx4 = (tid & 15) * 4;
    const int ty  = tid >> 4;

    float acc0[4], acc1[4];
    {
        float b0 = ob[0], b1 = ob[1];
        #pragma unroll
        for (int q = 0; q < 4; ++q) { acc0[q] = b0; acc1[q] = b1; }
    }

    f4 pA[2], pB[2];
    K1_LOAD(pA, 0);
    K1_WRITE(0, pA);
    K1_LOAD(pB, 1);
    __syncthreads();

#define K1_BODY(cc, PFL, PFW) do {                                      \
        if ((cc) + 2 < C) K1_LOAD(PFL, (cc) + 2);                       \
        const float* wap = ow + (cc) * 9;                               \
        const float* wbp = ow + (C + (cc)) * 9;                         \
        float wA[9], wB[9];                                             \
        _Pragma("unroll")                                               \
        for (int k = 0; k < 9; ++k) { wA[k] = wap[k]; wB[k] = wbp[k]; } \
        const float* buf = xs[(cc) & 1];                                \
        _Pragma("unroll")                                               \
        for (int ky = 0; ky < 3; ++ky) {                                \
            int base = (ty + ky) * K1S + tx4;                           \
            f4 A = *(const f4*)&buf[base];                              \
            f4 Bv = *(const f4*)&buf[base + 4];                         \
            float Cv = buf[base + 8];                                   \
            float in[6] = {A.w, Bv.x, Bv.y, Bv.z, Bv.w, Cv};            \
            _Pragma("unroll")                                           \
            for (int q = 0; q < 4; ++q) {                               \
                acc0[q] = fmaf(in[q], wA[ky*3+0], fmaf(in[q+1], wA[ky*3+1], fmaf(in[q+2], wA[ky*3+2], acc0[q]))); \
                acc1[q] = fmaf(in[q], wB[ky*3+0], fmaf(in[q+1], wB[ky*3+1], fmaf(in[q+2], wB[ky*3+2], acc1[q]))); \
            }                                                           \
        }                                                               \
        if ((cc) + 1 < C) K1_WRITE(((cc) + 1) & 1, PFW);                \
        __syncthreads();                                                \
    } while (0)

    for (int c = 0; c < C; c += 2) {
        K1_BODY(c,     pA, pB);
        K1_BODY(c + 1, pB, pA);
    }

    // tanh -> abs coords -> reflect -> store interleaved (ix,iy)
    const float sx = (float)W / (float)(W - 1);
    const float sy = (float)H / (float)(H - 1);
    const int hh = h0 + ty;
    float ixr[4], iyr[4];
    #pragma unroll
    for (int q = 0; q < 4; ++q) {
        float fx = (float)(w0 + tx4 + q) + fast_tanh(acc0[q]);
        float fy = (float)hh + fast_tanh(acc1[q]);
        ixr[q] = reflect_fast(fx * sx - 0.5f, (float)W);
        iyr[q] = reflect_fast(fy * sy - 0.5f, (float)H);
    }
    f4* p = (f4*)(ws + (size_t)b_ * HW + (size_t)hh * W + (w0 + tx4));
    f4 o0 = {ixr[0], iyr[0], ixr[1], iyr[1]};
    f4 o1 = {ixr[2], iyr[2], ixr[3], iyr[3]};
    p[0] = o0;
    p[1] = o1;
}

// ================= sample + depthwise conv (v6) =================
// 64x16 tile, NC=16 channels. xt double-buffered (clamped staging; clamped
// garbage only ever hit with weight exactly 0). Per-WAVE xd strips: wave wv
// owns output rows [4wv,4wv+4), samples pixel rows [4wv-1,4wv+5) x 66 cols
// into its private xd region -> sample->conv is an intra-wave dependency,
// no barrier. One barrier per channel (xt dbuf handoff). 2-deep prefetch.
#define NC 16
#define XTR 22
#define XTS 72
#define XT_SLOTS (XTR * 18)     // 396 f4 slots
#define XDS 68
#define XD_PER_WAVE (6 * XDS)   // 408 floats
#define SMP_N (6 * 66)          // 396 samples per wave

__global__ __launch_bounds__(256) void sample_dw_kernel(
        const float* __restrict__ x,
        const float2* __restrict__ ws,
        const float* __restrict__ dww,
        float* __restrict__ out) {
    __shared__ float xt[2][XTR * XTS];       // 12672 B
    __shared__ float xd[4][XD_PER_WAVE];     // 6528 B

    const int tid = threadIdx.x;
    const int bz = blockIdx.z;               // b*2 + cg
    const int b_ = bz >> 1;
    const int c0 = (bz & 1) * NC;
    const int h0 = blockIdx.y * 16;
    const int w0 = blockIdx.x * 64;
    const int wv = tid >> 6;
    const int lane = tid & 63;

    const float* xb = x + ((size_t)b_ * C + c0) * HW;
    const float2* wsb = ws + (size_t)b_ * HW;

    // channel-invariant staging descriptors (clamped)
    int s_goff[2], s_loff[2];
    bool s_ok[2];
    #pragma unroll
    for (int k = 0; k < 2; ++k) {
        int idx = tid + k * 256;
        s_ok[k] = (idx < XT_SLOTS);
        int row = idx / 18, k4 = idx - row * 18;
        int grow = min(max(h0 - 3 + row, 0), H - 1);
        int gcol = min(max(w0 - 4 + k4 * 4, 0), W - 4);
        s_goff[k] = grow * W + gcol;
        s_loff[k] = row * XTS + k4 * 4;
    }

#define K2_LOAD(PF, cc) do {                                            \
        const float* xc_ = xb + (size_t)(cc) * HW;                      \
        _Pragma("unroll")                                               \
        for (int k = 0; k < 2; ++k)                                     \
            if (s_ok[k]) PF[k] = *(const f4*)(xc_ + s_goff[k]);         \
    } while (0)
#define K2_WRITE(bufi, PF) do {                                         \
        float* dst_ = xt[bufi];                                         \
        _Pragma("unroll")                                               \
        for (int k = 0; k < 2; ++k)                                     \
            if (s_ok[k]) *(f4*)&dst_[s_loff[k]] = PF[k];                \
    } while (0)

    // per-wave sample meta in registers. ma: >=0 tap addr, -2 zero-fill,
    // -1 no slot.
    const int addr_base = (h0 - 3) * XTS + (w0 - 4);
    int   ma[7], xdo[7];
    float mwx[7], mwy[7];
    #pragma unroll
    for (int s = 0; s < 7; ++s) {
        int idx = s * 64 + lane;
        ma[s] = -1; xdo[s] = 0; mwx[s] = 0.f; mwy[s] = 0.f;
        if (idx < SMP_N) {
            int rr = idx / 66, q = idx - rr * 66;
            xdo[s] = rr * XDS + q;
            int hp = h0 + 4 * wv - 1 + rr;
            int wp = w0 - 1 + q;
            if (hp >= 0 && hp < H && wp >= 0 && wp < W) {
                float2 crd = wsb[hp * W + wp];
                float ix0f = floorf(crd.x), iy0f = floorf(crd.y);
                mwx[s] = crd.x - ix0f;
                mwy[s] = crd.y - iy0f;
                int ix0 = min(max((int)ix0f, 0), W - 1);
                int iy0 = min(max((int)iy0f, 0), H - 1);
                ma[s] = iy0 * XTS + ix0 - addr_base;
            } else {
                ma[s] = -2;
            }
        }
    }

    const int tx4 = (tid & 15) * 4;
    const int r   = (tid >> 4) & 3;          // row within wave strip
    float* xdw = xd[wv];

    f4 pA[2], pB[2];
    K2_LOAD(pA, 0);
    K2_WRITE(0, pA);
    K2_LOAD(pB, 1);
    __syncthreads();

#define K2_BODY(cc, PFL, PFW) do {                                      \
        if ((cc) + 2 < NC) K2_LOAD(PFL, (cc) + 2);                      \
        const float* cur = xt[(cc) & 1];                                \
        _Pragma("unroll")                                               \
        for (int s = 0; s < 7; ++s) {                                   \
            int a = ma[s];                                              \
            if (a != -1) {                                              \
                float v = 0.0f;                                         \
                if (a >= 0) {                                           \
                    float wx1 = mwx[s], wy1 = mwy[s];                   \
                    float wx0 = 1.0f - wx1, wy0 = 1.0f - wy1;           \
                    float v00 = cur[a];                                 \
                    float v01 = cur[a + 1];                             \
                    float v10 = cur[a + XTS];                           \
                    float v11 = cur[a + XTS + 1];                       \
                    v = (v00 * wx0 + v01 * wx1) * wy0                   \
                      + (v10 * wx0 + v11 * wx1) * wy1;                  \
                }                                                       \
                xdw[xdo[s]] = v;                                        \
            }                                                           \
        }                                                               \
        float wk[9];                                                    \
        const float* wc_ = dww + (size_t)(c0 + (cc)) * 9;               \
        _Pragma("unroll")                                               \
        for (int i = 0; i < 9; ++i) wk[i] = wc_[i];                     \
        float a4[4] = {0.f, 0.f, 0.f, 0.f};                             \
        _Pragma("unroll")                                               \
        for (int ky = 0; ky < 3; ++ky) {                                \
            int base = (r + ky) * XDS + tx4;                            \
            f4 A = *(const f4*)&xdw[base];                              \
            f2 D = *(const f2*)&xdw[base + 4];                          \
            float in[6] = {A.x, A.y, A.z, A.w, D.x, D.y};               \
            _Pragma("unroll")                                           \
            for (int q = 0; q < 4; ++q)                                 \
                a4[q] = fmaf(in[q], wk[ky*3+0], fmaf(in[q+1], wk[ky*3+1], fmaf(in[q+2], wk[ky*3+2], a4[q]))); \
        }                                                               \
        f4 res = {fmaxf(a4[0], 0.f), fmaxf(a4[1], 0.f),                 \
                  fmaxf(a4[2], 0.f), fmaxf(a4[3], 0.f)};                \
        float* op = out + ((size_t)b_ * C + c0 + (cc)) * HW             \
                  + (size_t)(h0 + 4 * wv + r) * W + (w0 + tx4);         \
        __builtin_nontemporal_store(res, (f4*)op);                      \
        if ((cc) + 1 < NC) K2_WRITE(((cc) + 1) & 1, PFW);               \
        __syncthreads();                                                \
    } while (0)

    for (int cc = 0; cc < NC; cc += 2) {
        K2_BODY(cc,     pA, pB);
        K2_BODY(cc + 1, pB, pA);
    }
}

extern "C" void kernel_launch(void* const* d_in, const int* in_sizes, int n_in,
                              void* d_out, int out_size, void* d_ws, size_t ws_size,
                              hipStream_t stream) {
    const float* x   = (const float*)d_in[0];
    const float* ow  = (const float*)d_in[1];
    const float* ob  = (const float*)d_in[2];
    const float* dww = (const float*)d_in[3];
    float* out = (float*)d_out;
    float2* ws = (float2*)d_ws;

    dim3 g1(W / 64, H / 16, B);
    offset_kernel<<<g1, 256, 0, stream>>>(x, ow, ob, ws);

    dim3 g2(W / 64, H / 16, B * (C / NC));
    sample_dw_kernel<<<g2, 256, 0, stream>>>(x, ws, dww, out);
}

// Round 7
// 139.101 us; speedup vs baseline: 1.0357x; 1.0357x over previous
//
#include <hip/hip_runtime.h>
#include <math.h>

#define B 8
#define C 32
#define H 384
#define W 384
#define HW (H*W)

typedef float f4 __attribute__((ext_vector_type(4)));
typedef float f2 __attribute__((ext_vector_type(2)));

// tanh via fast exp; offsets only shift sample coords, error negligible.
__device__ __forceinline__ float fast_tanh(float v) {
    float t = __expf(2.0f * v);
    return 1.0f - 2.0f / (t + 1.0f);
}

// Reflection over [-0.5, size-0.5] then clip. Drift |ix - w| <= 1.503 =>
// xr < 2*size, one fold suffices.
__device__ __forceinline__ float reflect_fast(float coord, float span) {
    float xr = fabsf(coord + 0.5f);
    float out = (xr < span) ? (xr - 0.5f) : (2.0f * span - xr - 0.5f);
    return fminf(fmaxf(out, 0.0f), span - 1.0f);
}

// ================= offset kernel (v7) =================
// 64x16 tile. Channel-PAIR per LDS stage (two planes), double-buffered:
// one barrier per pair (17 total vs 33). Zero-padded staging.
#define K1R 18
#define K1S 72
#define K1_SLOTS (K1R * 18)      // 324 f4 slots per plane

__global__ __launch_bounds__(256) void offset_kernel(
        const float* __restrict__ x,
        const float* __restrict__ ow,
        const float* __restrict__ ob,
        float2* __restrict__ ws) {
    __shared__ float xs[2][2][K1R * K1S];   // [buf][ch-in-pair] = 20736 B

    const int tid = threadIdx.x;
    const int b_ = blockIdx.z;
    const int h0 = blockIdx.y * 16;
    const int w0 = blockIdx.x * 64;
    const float* xb = x + (size_t)b_ * C * HW;

    int  goff[2], loff[2];
    bool gok[2], slot[2];
    #pragma unroll
    for (int k = 0; k < 2; ++k) {
        int idx = tid + k * 256;
        slot[k] = (idx < K1_SLOTS);
        int row = idx / 18, k4 = idx - row * 18;
        int grow = h0 - 1 + row;
        int gcol = w0 - 4 + k4 * 4;
        gok[k] = slot[k] && grow >= 0 && grow < H && gcol >= 0 && (gcol + 3) < W;
        goff[k] = max(grow, 0) * W + max(gcol, 0);
        loff[k] = row * K1S + k4 * 4;
    }

#define K1_LOADP(PF, p) do {                                             \
        const float* x0_ = xb + (size_t)(2 * (p)) * HW;                  \
        _Pragma("unroll")                                                \
        for (int k = 0; k < 2; ++k) {                                    \
            PF[k][0] = gok[k] ? *(const f4*)(x0_ + goff[k]) : (f4)0.0f;  \
            PF[k][1] = gok[k] ? *(const f4*)(x0_ + HW + goff[k]) : (f4)0.0f; \
        }                                                                \
    } while (0)
#define K1_WRITEP(bufi, PF) do {                                         \
        _Pragma("unroll")                                                \
        for (int k = 0; k < 2; ++k)                                      \
            if (slot[k]) {                                               \
                *(f4*)&xs[bufi][0][loff[k]] = PF[k][0];                  \
                *(f4*)&xs[bufi][1][loff[k]] = PF[k][1];                  \
            }                                                            \
    } while (0)

    const int tx4 = (tid & 15) * 4;
    const int ty  = tid >> 4;

    float acc0[4], acc1[4];
    {
        float b0 = ob[0], b1 = ob[1];
        #pragma unroll
        for (int q = 0; q < 4; ++q) { acc0[q] = b0; acc1[q] = b1; }
    }

#define K1_CONV(bufp, wf0, wf1) do {                                     \
        _Pragma("unroll")                                                \
        for (int ky = 0; ky < 3; ++ky) {                                 \
            int base = (ty + ky) * K1S + tx4;                            \
            f4 A = *(const f4*)&(bufp)[base];                            \
            f4 Bv = *(const f4*)&(bufp)[base + 4];                       \
            float Cv = (bufp)[base + 8];                                 \
            float in[6] = {A.w, Bv.x, Bv.y, Bv.z, Bv.w, Cv};             \
            _Pragma("unroll")                                            \
            for (int q = 0; q < 4; ++q) {                                \
                acc0[q] = fmaf(in[q], wf0[ky*3+0], fmaf(in[q+1], wf0[ky*3+1], fmaf(in[q+2], wf0[ky*3+2], acc0[q]))); \
                acc1[q] = fmaf(in[q], wf1[ky*3+0], fmaf(in[q+1], wf1[ky*3+1], fmaf(in[q+2], wf1[ky*3+2], acc1[q]))); \
            }                                                            \
        }                                                                \
    } while (0)

    f4 pf[2][2], pfN[2][2];
    K1_LOADP(pf, 0);
    K1_WRITEP(0, pf);
    __syncthreads();

    for (int p = 0; p < 16; ++p) {
        if (p + 1 < 16) K1_LOADP(pfN, p + 1);

        const int ca = 2 * p, cb = 2 * p + 1;
        const float* wa0p = ow + ca * 9;
        const float* wa1p = ow + (C + ca) * 9;
        const float* wb0p = ow + cb * 9;
        const float* wb1p = ow + (C + cb) * 9;
        float wa0[9], wa1[9], wb0[9], wb1[9];
        #pragma unroll
        for (int k = 0; k < 9; ++k) {
            wa0[k] = wa0p[k]; wa1[k] = wa1p[k];
            wb0[k] = wb0p[k]; wb1[k] = wb1p[k];
        }

        const float* bufa = xs[p & 1][0];
        const float* bufb = xs[p & 1][1];
        K1_CONV(bufa, wa0, wa1);
        K1_CONV(bufb, wb0, wb1);

        // write NEXT pair into the other buffer; one barrier per pair.
        if (p + 1 < 16) K1_WRITEP((p + 1) & 1, pfN);
        __syncthreads();
    }

    const float sx = (float)W / (float)(W - 1);
    const float sy = (float)H / (float)(H - 1);
    const int hh = h0 + ty;
    float ixr[4], iyr[4];
    #pragma unroll
    for (int q = 0; q < 4; ++q) {
        float fx = (float)(w0 + tx4 + q) + fast_tanh(acc0[q]);
        float fy = (float)hh + fast_tanh(acc1[q]);
        ixr[q] = reflect_fast(fx * sx - 0.5f, (float)W);
        iyr[q] = reflect_fast(fy * sy - 0.5f, (float)H);
    }
    f4* p = (f4*)(ws + (size_t)b_ * HW + (size_t)hh * W + (w0 + tx4));
    f4 o0 = {ixr[0], iyr[0], ixr[1], iyr[1]};
    f4 o1 = {ixr[2], iyr[2], ixr[3], iyr[3]};
    p[0] = o0;
    p[1] = o1;
}

// ================= sample + depthwise conv (v7) =================
// 64x16 tile, NC=16 channels as 8 channel-PAIRS. xt2: float2-per-pixel
// (two channels interleaved) -> one addr calc + aligned b64 taps serve both
// channels; xd2 float2 likewise. Shared xd (1188 samples), meta in regs.
// 2 barriers per pair (= 1 per channel). Clamped staging (clamped garbage
// only ever multiplied by weight exactly 0; zero-fill handles out-of-image).
#define NC 16
#define NPAIR (NC / 2)
#define XTR 22
#define XTS2 72                  // row stride in float2 px
#define XT_SLOTS (XTR * 18)      // 396 f4 slots per channel plane
#define XDS2 68
#define META_N (18 * 66)         // 1188

__global__ __launch_bounds__(256) void sample_dw_kernel(
        const float* __restrict__ x,
        const float2* __restrict__ ws,
        const float* __restrict__ dww,
        float* __restrict__ out) {
    __shared__ f2 xt2[XTR * XTS2];   // 12672 B
    __shared__ f2 xd2[18 * XDS2];    //  9792 B

    const int tid = threadIdx.x;
    const int bz = blockIdx.z;       // b*2 + cg
    const int b_ = bz >> 1;
    const int c0 = (bz & 1) * NC;
    const int h0 = blockIdx.y * 16;
    const int w0 = blockIdx.x * 64;

    const float* xb = x + ((size_t)b_ * C + c0) * HW;
    const float2* wsb = ws + (size_t)b_ * HW;

    // channel-invariant staging descriptors (clamped)
    int s_goff[2], s_l2[2];
    bool s_ok[2];
    #pragma unroll
    for (int k = 0; k < 2; ++k) {
        int idx = tid + k * 256;
        s_ok[k] = (idx < XT_SLOTS);
        int row = idx / 18, k4 = idx - row * 18;
        int grow = min(max(h0 - 3 + row, 0), H - 1);
        int gcol = min(max(w0 - 4 + k4 * 4, 0), W - 4);
        s_goff[k] = grow * W + gcol;
        s_l2[k] = row * XTS2 + k4 * 4;       // f2 index
    }

#define K2_LOADP(PF, p) do {                                             \
        const float* xc_ = xb + (size_t)(2 * (p)) * HW;                  \
        _Pragma("unroll")                                                \
        for (int k = 0; k < 2; ++k)                                      \
            if (s_ok[k]) {                                               \
                PF[k][0] = *(const f4*)(xc_ + s_goff[k]);                \
                PF[k][1] = *(const f4*)(xc_ + HW + s_goff[k]);           \
            }                                                            \
    } while (0)
// interleave (a0,b0,a1,b1),(a2,b2,a3,b3) -> two b128 writes
#define K2_WRITEP(PF) do {                                               \
        _Pragma("unroll")                                                \
        for (int k = 0; k < 2; ++k)                                      \
            if (s_ok[k]) {                                               \
                f4 w0v = {PF[k][0].x, PF[k][1].x, PF[k][0].y, PF[k][1].y}; \
                f4 w1v = {PF[k][0].z, PF[k][1].z, PF[k][0].w, PF[k][1].w}; \
                *(f4*)&xt2[s_l2[k]] = w0v;                               \
                *(f4*)&xt2[s_l2[k] + 2] = w1v;                           \
            }                                                            \
    } while (0)

    // per-pixel meta in registers (same thread writes & consumes index i)
    const int addr_base = (h0 - 3) * XTS2 + (w0 - 4);
    int   ma[5], xdo[5];
    float mwx[5], mwy[5];

    // prologue: load pair 0, compute meta (hides load latency), stage, sync
    f4 pf[2][2], pfN[2][2];
    K2_LOADP(pf, 0);

    #pragma unroll
    for (int k = 0; k < 5; ++k) {
        int i = tid + k * 256;
        ma[k] = -1; xdo[k] = 0; mwx[k] = 0.f; mwy[k] = 0.f;
        if (i < META_N) {
            int r = i / 66, q = i - r * 66;
            xdo[k] = r * XDS2 + q;
            int hp = h0 - 1 + r, wp = w0 - 1 + q;
            if (hp >= 0 && hp < H && wp >= 0 && wp < W) {
                float2 crd = wsb[hp * W + wp];
                float ix0f = floorf(crd.x), iy0f = floorf(crd.y);
                mwx[k] = crd.x - ix0f;
                mwy[k] = crd.y - iy0f;
                int ix0 = min(max((int)ix0f, 0), W - 1);
                int iy0 = min(max((int)iy0f, 0), H - 1);
                ma[k] = iy0 * XTS2 + ix0 - addr_base;
            } else {
                ma[k] = -2;                   // in tile, zero value
            }
        }
    }

    K2_WRITEP(pf);
    __syncthreads();

    const int tx4 = (tid & 15) * 4;
    const int ty  = tid >> 4;

    for (int p = 0; p < NPAIR; ++p) {
        if (p + 1 < NPAIR) K2_LOADP(pfN, p + 1);

        // bilinear sample (both channels at once) xt2 -> xd2
        #pragma unroll
        for (int k = 0; k < 5; ++k) {
            int a = ma[k];
            if (a != -1) {
                f2 v = {0.f, 0.f};
                if (a >= 0) {
                    float wx1 = mwx[k], wy1 = mwy[k];
                    float wx0 = 1.0f - wx1, wy0 = 1.0f - wy1;
                    f2 t00 = xt2[a];
                    f2 t01 = xt2[a + 1];
                    f2 t10 = xt2[a + XTS2];
                    f2 t11 = xt2[a + XTS2 + 1];
                    v = (t00 * wx0 + t01 * wx1) * wy0
                      + (t10 * wx0 + t11 * wx1) * wy1;
                }
                xd2[xdo[k]] = v;
            }
        }

        // weights for both channels (wave-uniform -> scalar)
        float wk0[9], wk1[9];
        {
            const float* wc0 = dww + (size_t)(c0 + 2 * p) * 9;
            #pragma unroll
            for (int i = 0; i < 9; ++i) { wk0[i] = wc0[i]; wk1[i] = wc0[9 + i]; }
        }

        __syncthreads();   // xd2 complete; xt2 fully consumed

        // 3x3 depthwise conv for both channels: 1 row x 4 cols per thread
        float a0[4] = {0.f, 0.f, 0.f, 0.f};
        float a1[4] = {0.f, 0.f, 0.f, 0.f};
        #pragma unroll
        for (int ky = 0; ky < 3; ++ky) {
            int ro = (ty + ky) * XDS2 + tx4;
            f4 P0 = *(const f4*)&xd2[ro];
            f4 P1 = *(const f4*)&xd2[ro + 2];
            f4 P2 = *(const f4*)&xd2[ro + 4];
            float in0[6] = {P0.x, P0.z, P1.x, P1.z, P2.x, P2.z};
            float in1[6] = {P0.y, P0.w, P1.y, P1.w, P2.y, P2.w};
            #pragma unroll
            for (int q = 0; q < 4; ++q) {
                a0[q] = fmaf(in0[q], wk0[ky*3+0], fmaf(in0[q+1], wk0[ky*3+1], fmaf(in0[q+2], wk0[ky*3+2], a0[q])));
                a1[q] = fmaf(in1[q], wk1[ky*3+0], fmaf(in1[q+1], wk1[ky*3+1], fmaf(in1[q+2], wk1[ky*3+2], a1[q])));
            }
        }
        f4 r0 = {fmaxf(a0[0], 0.f), fmaxf(a0[1], 0.f), fmaxf(a0[2], 0.f), fmaxf(a0[3], 0.f)};
        f4 r1 = {fmaxf(a1[0], 0.f), fmaxf(a1[1], 0.f), fmaxf(a1[2], 0.f), fmaxf(a1[3], 0.f)};
        float* op0 = out + ((size_t)b_ * C + c0 + 2 * p) * HW
                   + (size_t)(h0 + ty) * W + (w0 + tx4);
        __builtin_nontemporal_store(r0, (f4*)op0);
        __builtin_nontemporal_store(r1, (f4*)(op0 + HW));

        // stage next pair (xt2 readers all past the barrier above)
        if (p + 1 < NPAIR) {
            K2_WRITEP(pfN);
        }
        __syncthreads();   // xt2 ready for next pair's sampling
    }
}

extern "C" void kernel_launch(void* const* d_in, const int* in_sizes, int n_in,
                              void* d_out, int out_size, void* d_ws, size_t ws_size,
                              hipStream_t stream) {
    const float* x   = (const float*)d_in[0];
    const float* ow  = (const float*)d_in[1];
    const float* ob  = (const float*)d_in[2];
    const float* dww = (const float*)d_in[3];
    float* out = (float*)d_out;
    float2* ws = (float2*)d_ws;

    dim3 g1(W / 64, H / 16, B);
    offset_kernel<<<g1, 256, 0, stream>>>(x, ow, ob, ws);

    dim3 g2(W / 64, H / 16, B * (C / NC));
    sample_dw_kernel<<<g2, 256, 0, stream>>>(x, ws, dww, out);
}

// Round 8
// 136.041 us; speedup vs baseline: 1.0590x; 1.0225x over previous
//
#include <hip/hip_runtime.h>
#include <math.h>

#define B 8
#define C 32
#define H 384
#define W 384
#define HW (H*W)

typedef float f4 __attribute__((ext_vector_type(4)));
typedef float f2 __attribute__((ext_vector_type(2)));

// tanh via fast exp; offsets only shift sample coords, error negligible.
__device__ __forceinline__ float fast_tanh(float v) {
    float t = __expf(2.0f * v);
    return 1.0f - 2.0f / (t + 1.0f);
}

// Reflection over [-0.5, size-0.5] then clip. Drift |ix - w| <= 1.503 =>
// xr < 2*size, one fold suffices.
__device__ __forceinline__ float reflect_fast(float coord, float span) {
    float xr = fabsf(coord + 0.5f);
    float out = (xr < span) ? (xr - 0.5f) : (2.0f * span - xr - 0.5f);
    return fminf(fmaxf(out, 0.0f), span - 1.0f);
}

// ================= offset kernel (v7, unchanged) =================
// 64x16 tile. Channel-PAIR per LDS stage (two planes), double-buffered:
// one barrier per pair. Zero-padded staging.
#define K1R 18
#define K1S 72
#define K1_SLOTS (K1R * 18)      // 324 f4 slots per plane

__global__ __launch_bounds__(256) void offset_kernel(
        const float* __restrict__ x,
        const float* __restrict__ ow,
        const float* __restrict__ ob,
        float2* __restrict__ ws) {
    __shared__ float xs[2][2][K1R * K1S];   // [buf][ch-in-pair] = 20736 B

    const int tid = threadIdx.x;
    const int b_ = blockIdx.z;
    const int h0 = blockIdx.y * 16;
    const int w0 = blockIdx.x * 64;
    const float* xb = x + (size_t)b_ * C * HW;

    int  goff[2], loff[2];
    bool gok[2], slot[2];
    #pragma unroll
    for (int k = 0; k < 2; ++k) {
        int idx = tid + k * 256;
        slot[k] = (idx < K1_SLOTS);
        int row = idx / 18, k4 = idx - row * 18;
        int grow = h0 - 1 + row;
        int gcol = w0 - 4 + k4 * 4;
        gok[k] = slot[k] && grow >= 0 && grow < H && gcol >= 0 && (gcol + 3) < W;
        goff[k] = max(grow, 0) * W + max(gcol, 0);
        loff[k] = row * K1S + k4 * 4;
    }

#define K1_LOADP(PF, p) do {                                             \
        const float* x0_ = xb + (size_t)(2 * (p)) * HW;                  \
        _Pragma("unroll")                                                \
        for (int k = 0; k < 2; ++k) {                                    \
            PF[k][0] = gok[k] ? *(const f4*)(x0_ + goff[k]) : (f4)0.0f;  \
            PF[k][1] = gok[k] ? *(const f4*)(x0_ + HW + goff[k]) : (f4)0.0f; \
        }                                                                \
    } while (0)
#define K1_WRITEP(bufi, PF) do {                                         \
        _Pragma("unroll")                                                \
        for (int k = 0; k < 2; ++k)                                      \
            if (slot[k]) {                                               \
                *(f4*)&xs[bufi][0][loff[k]] = PF[k][0];                  \
                *(f4*)&xs[bufi][1][loff[k]] = PF[k][1];                  \
            }                                                            \
    } while (0)

    const int tx4 = (tid & 15) * 4;
    const int ty  = tid >> 4;

    float acc0[4], acc1[4];
    {
        float b0 = ob[0], b1 = ob[1];
        #pragma unroll
        for (int q = 0; q < 4; ++q) { acc0[q] = b0; acc1[q] = b1; }
    }

#define K1_CONV(bufp, wf0, wf1) do {                                     \
        _Pragma("unroll")                                                \
        for (int ky = 0; ky < 3; ++ky) {                                 \
            int base = (ty + ky) * K1S + tx4;                            \
            f4 A = *(const f4*)&(bufp)[base];                            \
            f4 Bv = *(const f4*)&(bufp)[base + 4];                       \
            float Cv = (bufp)[base + 8];                                 \
            float in[6] = {A.w, Bv.x, Bv.y, Bv.z, Bv.w, Cv};             \
            _Pragma("unroll")                                            \
            for (int q = 0; q < 4; ++q) {                                \
                acc0[q] = fmaf(in[q], wf0[ky*3+0], fmaf(in[q+1], wf0[ky*3+1], fmaf(in[q+2], wf0[ky*3+2], acc0[q]))); \
                acc1[q] = fmaf(in[q], wf1[ky*3+0], fmaf(in[q+1], wf1[ky*3+1], fmaf(in[q+2], wf1[ky*3+2], acc1[q]))); \
            }                                                            \
        }                                                                \
    } while (0)

    f4 pf[2][2], pfN[2][2];
    K1_LOADP(pf, 0);
    K1_WRITEP(0, pf);
    __syncthreads();

    for (int p = 0; p < 16; ++p) {
        if (p + 1 < 16) K1_LOADP(pfN, p + 1);

        const int ca = 2 * p, cb = 2 * p + 1;
        const float* wa0p = ow + ca * 9;
        const float* wa1p = ow + (C + ca) * 9;
        const float* wb0p = ow + cb * 9;
        const float* wb1p = ow + (C + cb) * 9;
        float wa0[9], wa1[9], wb0[9], wb1[9];
        #pragma unroll
        for (int k = 0; k < 9; ++k) {
            wa0[k] = wa0p[k]; wa1[k] = wa1p[k];
            wb0[k] = wb0p[k]; wb1[k] = wb1p[k];
        }

        const float* bufa = xs[p & 1][0];
        const float* bufb = xs[p & 1][1];
        K1_CONV(bufa, wa0, wa1);
        K1_CONV(bufb, wb0, wb1);

        if (p + 1 < 16) K1_WRITEP((p + 1) & 1, pfN);
        __syncthreads();
    }

    const float sx = (float)W / (float)(W - 1);
    const float sy = (float)H / (float)(H - 1);
    const int hh = h0 + ty;
    float ixr[4], iyr[4];
    #pragma unroll
    for (int q = 0; q < 4; ++q) {
        float fx = (float)(w0 + tx4 + q) + fast_tanh(acc0[q]);
        float fy = (float)hh + fast_tanh(acc1[q]);
        ixr[q] = reflect_fast(fx * sx - 0.5f, (float)W);
        iyr[q] = reflect_fast(fy * sy - 0.5f, (float)H);
    }
    f4* p = (f4*)(ws + (size_t)b_ * HW + (size_t)hh * W + (w0 + tx4));
    f4 o0 = {ixr[0], iyr[0], ixr[1], iyr[1]};
    f4 o1 = {ixr[2], iyr[2], ixr[3], iyr[3]};
    p[0] = o0;
    p[1] = o1;
}

// ================= sample + depthwise conv (v8) =================
// R4 structure (best measured: 85us) consolidated:
//  - NC=8 -> 4608 blocks (occupancy; R4-proven)
//  - meta in registers (R5-proven, -14KB LDS)
//  - PLANAR f32 xt, double-buffered: taps via ds_read2_b32 on consecutive
//    addrs -> 2 lanes/bank = conflict-free
//  - planar xd, conv reads f4+f2 (dense, conflict-free), scalar xd writes
//  - 2 barriers/channel, 1-ahead register prefetch, nt stores
#define NC 8
#define XTR 22
#define XTS 72
#define XT_SLOTS (XTR * 18)     // 396 f4 slots
#define XDS 68
#define META_N (18 * 66)        // 1188

__global__ __launch_bounds__(256) void sample_dw_kernel(
        const float* __restrict__ x,
        const float2* __restrict__ ws,
        const float* __restrict__ dww,
        float* __restrict__ out) {
    __shared__ float xt[2][XTR * XTS];   // 12672 B
    __shared__ float xd[18 * XDS];       //  4896 B

    const int tid = threadIdx.x;
    const int bz = blockIdx.z;           // b*4 + cg
    const int b_ = bz >> 2;
    const int c0 = (bz & 3) * NC;
    const int h0 = blockIdx.y * 16;
    const int w0 = blockIdx.x * 64;

    const float* xb = x + ((size_t)b_ * C + c0) * HW;
    const float2* wsb = ws + (size_t)b_ * HW;

    // channel-invariant staging descriptors (clamped; clamped garbage is
    // only ever multiplied by weight exactly 0 via the zero-fill path)
    int s_goff[2], s_loff[2];
    bool s_ok[2];
    #pragma unroll
    for (int k = 0; k < 2; ++k) {
        int idx = tid + k * 256;
        s_ok[k] = (idx < XT_SLOTS);
        int row = idx / 18, k4 = idx - row * 18;
        int grow = min(max(h0 - 3 + row, 0), H - 1);
        int gcol = min(max(w0 - 4 + k4 * 4, 0), W - 4);
        s_goff[k] = grow * W + gcol;
        s_loff[k] = row * XTS + k4 * 4;
    }

#define K2_LOAD(PF, cc) do {                                            \
        const float* xc_ = xb + (size_t)(cc) * HW;                      \
        _Pragma("unroll")                                               \
        for (int k = 0; k < 2; ++k)                                     \
            if (s_ok[k]) PF[k] = *(const f4*)(xc_ + s_goff[k]);         \
    } while (0)
#define K2_WRITE(bufi, PF) do {                                         \
        float* dst_ = xt[bufi];                                         \
        _Pragma("unroll")                                               \
        for (int k = 0; k < 2; ++k)                                     \
            if (s_ok[k]) *(f4*)&dst_[s_loff[k]] = PF[k];                \
    } while (0)

    // prologue: load ch0; meta compute hides the load latency
    f4 pA[2], pB[2];
    K2_LOAD(pA, 0);

    // per-pixel meta in registers (same thread writes & consumes index i)
    const int addr_base = (h0 - 3) * XTS + (w0 - 4);
    int   ma[5], xdo[5];
    float mwx[5], mwy[5];
    #pragma unroll
    for (int k = 0; k < 5; ++k) {
        int i = tid + k * 256;
        ma[k] = -1; xdo[k] = 0; mwx[k] = 0.f; mwy[k] = 0.f;
        if (i < META_N) {
            int r = i / 66, q = i - r * 66;
            xdo[k] = r * XDS + q;
            int hp = h0 - 1 + r, wp = w0 - 1 + q;
            if (hp >= 0 && hp < H && wp >= 0 && wp < W) {
                float2 crd = wsb[hp * W + wp];
                float ix0f = floorf(crd.x), iy0f = floorf(crd.y);
                mwx[k] = crd.x - ix0f;
                mwy[k] = crd.y - iy0f;
                int ix0 = min(max((int)ix0f, 0), W - 1);
                int iy0 = min(max((int)iy0f, 0), H - 1);
                ma[k] = iy0 * XTS + ix0 - addr_base;
            } else {
                ma[k] = -2;                   // in tile, zero value
            }
        }
    }

    K2_WRITE(0, pA);
    K2_LOAD(pB, 1);
    __syncthreads();

    const int tx4 = (tid & 15) * 4;
    const int ty  = tid >> 4;

    // iter cc: xt[cc&1] holds ch cc; PFW holds ch cc+1; PFL gets ch cc+2.
#define K2_BODY(cc, PFL, PFW) do {                                      \
        if ((cc) + 2 < NC) K2_LOAD(PFL, (cc) + 2);                      \
        const float* cur = xt[(cc) & 1];                                \
        _Pragma("unroll")                                               \
        for (int s = 0; s < 5; ++s) {                                   \
            int a = ma[s];                                              \
            if (a != -1) {                                              \
                float v = 0.0f;                                         \
                if (a >= 0) {                                           \
                    float wx1 = mwx[s], wy1 = mwy[s];                   \
                    float wx0 = 1.0f - wx1, wy0 = 1.0f - wy1;           \
                    float v00 = cur[a];                                 \
                    float v01 = cur[a + 1];                             \
                    float v10 = cur[a + XTS];                           \
                    float v11 = cur[a + XTS + 1];                       \
                    v = (v00 * wx0 + v01 * wx1) * wy0                   \
                      + (v10 * wx0 + v11 * wx1) * wy1;                  \
                }                                                       \
                xd[xdo[s]] = v;                                         \
            }                                                           \
        }                                                               \
        float wk[9];                                                    \
        const float* wc_ = dww + (size_t)(c0 + (cc)) * 9;               \
        _Pragma("unroll")                                               \
        for (int i = 0; i < 9; ++i) wk[i] = wc_[i];                     \
        if ((cc) + 1 < NC) K2_WRITE(((cc) + 1) & 1, PFW);               \
        __syncthreads();   /* xd ready; xt[next] staged */              \
        float a4[4] = {0.f, 0.f, 0.f, 0.f};                             \
        _Pragma("unroll")                                               \
        for (int ky = 0; ky < 3; ++ky) {                                \
            int base = (ty + ky) * XDS + tx4;                           \
            f4 A = *(const f4*)&xd[base];                               \
            f2 D = *(const f2*)&xd[base + 4];                           \
            float in[6] = {A.x, A.y, A.z, A.w, D.x, D.y};               \
            _Pragma("unroll")                                           \
            for (int q = 0; q < 4; ++q)                                 \
                a4[q] = fmaf(in[q], wk[ky*3+0], fmaf(in[q+1], wk[ky*3+1], fmaf(in[q+2], wk[ky*3+2], a4[q]))); \
        }                                                               \
        f4 res = {fmaxf(a4[0], 0.f), fmaxf(a4[1], 0.f),                 \
                  fmaxf(a4[2], 0.f), fmaxf(a4[3], 0.f)};                \
        float* op = out + ((size_t)b_ * C + c0 + (cc)) * HW             \
                  + (size_t)(h0 + ty) * W + (w0 + tx4);                 \
        __builtin_nontemporal_store(res, (f4*)op);                      \
        __syncthreads();   /* conv done before next xd overwrite */     \
    } while (0)

    for (int cc = 0; cc < NC; cc += 2) {
        K2_BODY(cc,     pA, pB);
        K2_BODY(cc + 1, pB, pA);
    }
}

extern "C" void kernel_launch(void* const* d_in, const int* in_sizes, int n_in,
                              void* d_out, int out_size, void* d_ws, size_t ws_size,
                              hipStream_t stream) {
    const float* x   = (const float*)d_in[0];
    const float* ow  = (const float*)d_in[1];
    const float* ob  = (const float*)d_in[2];
    const float* dww = (const float*)d_in[3];
    float* out = (float*)d_out;
    float2* ws = (float2*)d_ws;

    dim3 g1(W / 64, H / 16, B);
    offset_kernel<<<g1, 256, 0, stream>>>(x, ow, ob, ws);

    dim3 g2(W / 64, H / 16, B * (C / NC));
    sample_dw_kernel<<<g2, 256, 0, stream>>>(x, ws, dww, out);
}